// Round 1
// baseline (326.836 us; speedup 1.0000x reference)
//
#include <hip/hip_runtime.h>

typedef unsigned short ushort_t;

#define B_ 64
#define S_ 512
#define E_ 256
#define H_ 128
#define M_ (B_ * S_)   // 32768 rows
#define CAP_ 128       // max neighbor slots

// ---------------------------------------------------------------------------
// K1: neighbor lists from binary adj (float4 reads) + invdeg = 1/(nnz+1)
// ---------------------------------------------------------------------------
__global__ void k_adjidx(const float* __restrict__ adj,
                         ushort_t* __restrict__ idxl,
                         int* __restrict__ nnz,
                         float* __restrict__ invdeg) {
    int row  = blockIdx.x * 4 + (threadIdx.x >> 6);
    int lane = threadIdx.x & 63;
    const float4* arow = (const float4*)(adj + (size_t)row * S_);
    ushort_t* dst = idxl + (size_t)row * CAP_;
    int total = 0;
    #pragma unroll
    for (int c = 0; c < 2; ++c) {
        float4 v = arow[c * 64 + lane];
        float f[4] = {v.x, v.y, v.z, v.w};
        #pragma unroll
        for (int j = 0; j < 4; ++j) {
            unsigned long long m = __ballot(f[j] != 0.0f);
            if (f[j] != 0.0f) {
                int pos = total + __popcll(m & ((1ull << lane) - 1ull));
                if (pos < CAP_) dst[pos] = (ushort_t)(c * 256 + lane * 4 + j);
            }
            total += __popcll(m);
        }
    }
    if (lane == 0) {
        nnz[row] = total < CAP_ ? total : CAP_;
        invdeg[row] = 1.0f / (float)(total + 1);
    }
}

// ---------------------------------------------------------------------------
// K2: fused layer. One block = (batch b, 32-col group cg).
//   Phase A: Ys[512][32] = X[b] @ W[cols]^T   (k-major X slab double-buffered
//            through LDS, 8x8 micro-tile per thread, 1 barrier per 8-k chunk)
//   Phase B: h = relu((Ys[r] + sum_nbr Ys[t] + 2b) * invdeg)  gathered from
//            LDS (stride 36 floats -> bank-quad balanced), written to global
//            (!POOL) or max-pooled fully in-block (POOL).
// 256 blocks (1/CU), 256 threads. LDS = 72K(Ys) + 32K(Xs) + 2K(Wsh) = 106.5K.
// XCD swizzle: batch b's 4 col-blocks share xcd = b&7 (h slab L2-local).
// ---------------------------------------------------------------------------
template <int K, bool GATHER, bool POOL>
__global__ __launch_bounds__(256, 1)
void k_layer(const float* __restrict__ X, const int* __restrict__ sent,
             const float* __restrict__ emb, const float* __restrict__ W,
             const ushort_t* __restrict__ idxl, const int* __restrict__ nnz,
             const float* __restrict__ invdeg, const float* __restrict__ bias,
             float* __restrict__ out) {
    __shared__ __align__(16) float Ys[S_ * 36];       // 73728 B, row stride 36
    __shared__ __align__(16) float Xs[2][8 * S_];     // 32768 B, k-major
    __shared__ __align__(16) float Wsh[2][8 * 32];    // 2048 B,  k-major

    const int tid = threadIdx.x;
    const int bid = blockIdx.x;
    const int xcd = bid & 7, slot = bid >> 3;
    const int b = xcd + 8 * (slot >> 2);
    const int cg = slot & 3;
    const int colBase = cg * 32;
    const int rowBase = b * S_;

    // ---- Phase A: GEMM ----
    // staging: thread loads 4 float4 (rows row0+128q, k-quarter kq)
    const int row0 = tid >> 1;            // 0..127
    const int kq   = (tid & 1) * 4;       // 0 or 4
    const float* xp[4];
    #pragma unroll
    for (int q = 0; q < 4; ++q) {
        const int r = row0 + 128 * q;
        const float* src;
        if (GATHER) src = emb + (size_t)sent[rowBase + r] * K;
        else        src = X + (size_t)(rowBase + r) * K;
        xp[q] = src + kq;
    }
    const int wcol = (tid >> 1) & 31;
    const float* wp = W + (size_t)(colBase + wcol) * K + kq;

    // compute mapping: rows {rg4..rg4+3, 256+rg4..+3}, cols c0..c0+7
    const int rg4 = tid & ~3;             // 0..252
    const int c0  = (tid & 3) * 8;

    float acc[8][8] = {};
    float4 g[4];
    float4 wv = {0.f, 0.f, 0.f, 0.f};

    constexpr int NC = K / 8;

    // prologue: stage chunk 0
    #pragma unroll
    for (int q = 0; q < 4; ++q) g[q] = *(const float4*)(xp[q]);
    if (tid < 64) wv = *(const float4*)(wp);
    #pragma unroll
    for (int q = 0; q < 4; ++q) {
        const int pr = row0 + 128 * q;
        Xs[0][(kq + 0) * 512 + pr] = g[q].x;
        Xs[0][(kq + 1) * 512 + pr] = g[q].y;
        Xs[0][(kq + 2) * 512 + pr] = g[q].z;
        Xs[0][(kq + 3) * 512 + pr] = g[q].w;
    }
    if (tid < 64) {
        Wsh[0][(kq + 0) * 32 + wcol] = wv.x;
        Wsh[0][(kq + 1) * 32 + wcol] = wv.y;
        Wsh[0][(kq + 2) * 32 + wcol] = wv.z;
        Wsh[0][(kq + 3) * 32 + wcol] = wv.w;
    }
    __syncthreads();

    #pragma unroll 1
    for (int c = 0; c < NC; ++c) {
        const int cur = c & 1;
        if (c + 1 < NC) {   // prefetch next chunk (global -> regs)
            #pragma unroll
            for (int q = 0; q < 4; ++q) g[q] = *(const float4*)(xp[q] + (c + 1) * 8);
            if (tid < 64) wv = *(const float4*)(wp + (c + 1) * 8);
        }
        #pragma unroll
        for (int k = 0; k < 8; ++k) {
            const float4 xa = *(const float4*)&Xs[cur][k * 512 + rg4];
            const float4 xb = *(const float4*)&Xs[cur][k * 512 + 256 + rg4];
            const float4 wa = *(const float4*)&Wsh[cur][k * 32 + c0];
            const float4 wb = *(const float4*)&Wsh[cur][k * 32 + c0 + 4];
            const float xv[8]  = {xa.x, xa.y, xa.z, xa.w, xb.x, xb.y, xb.z, xb.w};
            const float wv8[8] = {wa.x, wa.y, wa.z, wa.w, wb.x, wb.y, wb.z, wb.w};
            #pragma unroll
            for (int i = 0; i < 8; ++i)
                #pragma unroll
                for (int j = 0; j < 8; ++j)
                    acc[i][j] += xv[i] * wv8[j];
        }
        if (c + 1 < NC) {   // regs -> other LDS buffer
            const int nb = cur ^ 1;
            #pragma unroll
            for (int q = 0; q < 4; ++q) {
                const int pr = row0 + 128 * q;
                Xs[nb][(kq + 0) * 512 + pr] = g[q].x;
                Xs[nb][(kq + 1) * 512 + pr] = g[q].y;
                Xs[nb][(kq + 2) * 512 + pr] = g[q].z;
                Xs[nb][(kq + 3) * 512 + pr] = g[q].w;
            }
            if (tid < 64) {
                Wsh[nb][(kq + 0) * 32 + wcol] = wv.x;
                Wsh[nb][(kq + 1) * 32 + wcol] = wv.y;
                Wsh[nb][(kq + 2) * 32 + wcol] = wv.z;
                Wsh[nb][(kq + 3) * 32 + wcol] = wv.w;
            }
        }
        __syncthreads();
    }

    // epilogue: acc -> Ys slab
    #pragma unroll
    for (int i = 0; i < 8; ++i) {
        const int r = (i < 4) ? (rg4 + i) : (256 + rg4 + i - 4);
        *(float4*)&Ys[r * 36 + c0]     = make_float4(acc[i][0], acc[i][1], acc[i][2], acc[i][3]);
        *(float4*)&Ys[r * 36 + c0 + 4] = make_float4(acc[i][4], acc[i][5], acc[i][6], acc[i][7]);
    }
    __syncthreads();

    // ---- Phase B: LDS neighbor aggregation (+bias, invdeg, relu) ----
    const int rsub = tid >> 3;     // 0..31 rows in flight
    const int cc   = tid & 7;      // float4 chunk of the 32-col slab
    const float4* Ys4 = (const float4*)Ys;
    const float4 bv = *(const float4*)(bias + colBase + cc * 4);
    float4 pmax = {0.f, 0.f, 0.f, 0.f};   // post-relu values are >= 0

    #pragma unroll 1
    for (int p = 0; p < 16; ++p) {
        const int r = p * 32 + rsub;
        const int grow = rowBase + r;
        const int n = nnz[grow];
        const ushort_t* il = idxl + (size_t)grow * CAP_;
        float4 a = Ys4[r * 9 + cc];
        float4 a2 = {0.f, 0.f, 0.f, 0.f};
        int i = 0;
        for (; i + 4 <= n; i += 4) {
            const unsigned long long pk = *(const unsigned long long*)(il + i);
            const int t0 = (int)(pk & 0xffffu);
            const int t1 = (int)((pk >> 16) & 0xffffu);
            const int t2 = (int)((pk >> 32) & 0xffffu);
            const int t3 = (int)((pk >> 48) & 0xffffu);
            const float4 v0 = Ys4[t0 * 9 + cc];
            const float4 v1 = Ys4[t1 * 9 + cc];
            const float4 v2 = Ys4[t2 * 9 + cc];
            const float4 v3 = Ys4[t3 * 9 + cc];
            a.x += v0.x + v1.x;  a.y += v0.y + v1.y;
            a.z += v0.z + v1.z;  a.w += v0.w + v1.w;
            a2.x += v2.x + v3.x; a2.y += v2.y + v3.y;
            a2.z += v2.z + v3.z; a2.w += v2.w + v3.w;
        }
        for (; i < n; ++i) {
            const int t = il[i];
            const float4 v = Ys4[t * 9 + cc];
            a.x += v.x; a.y += v.y; a.z += v.z; a.w += v.w;
        }
        a.x += a2.x; a.y += a2.y; a.z += a2.z; a.w += a2.w;
        const float inv = invdeg[grow];
        float4 o;
        o.x = fmaxf((a.x + 2.0f * bv.x) * inv, 0.0f);
        o.y = fmaxf((a.y + 2.0f * bv.y) * inv, 0.0f);
        o.z = fmaxf((a.z + 2.0f * bv.z) * inv, 0.0f);
        o.w = fmaxf((a.w + 2.0f * bv.w) * inv, 0.0f);
        if (!POOL) {
            *(float4*)(out + (size_t)grow * H_ + colBase + cc * 4) = o;
        } else {
            pmax.x = fmaxf(pmax.x, o.x); pmax.y = fmaxf(pmax.y, o.y);
            pmax.z = fmaxf(pmax.z, o.z); pmax.w = fmaxf(pmax.w, o.w);
        }
    }

    if (POOL) {
        // full in-block pool: reduce the 32 row-groups (reuse Xs as scratch)
        float4* smax = (float4*)Xs;
        smax[rsub * 8 + cc] = pmax;
        __syncthreads();
        if (tid < 8) {
            float4 m = smax[tid];
            #pragma unroll 8
            for (int q = 1; q < 32; ++q) {
                const float4 v = smax[q * 8 + tid];
                m.x = fmaxf(m.x, v.x); m.y = fmaxf(m.y, v.y);
                m.z = fmaxf(m.z, v.z); m.w = fmaxf(m.w, v.w);
            }
            *(float4*)(out + (size_t)b * H_ + colBase + tid * 4) = m;
        }
    }
}

// ---------------------------------------------------------------------------
// K3: logits[b,c] = pooled[b,:] . Wp[c,:] + bp[c]   (pooled is [64][128])
// ---------------------------------------------------------------------------
__global__ void k_final(const float* __restrict__ pooled,
                        const float* __restrict__ Wp,
                        const float* __restrict__ bp,
                        float* __restrict__ out) {
    int b = blockIdx.x, j = threadIdx.x;  // 128 threads
    float m = pooled[(size_t)b * H_ + j];
    float t0 = m * Wp[j];
    float t1 = m * Wp[H_ + j];
    #pragma unroll
    for (int off = 32; off > 0; off >>= 1) {
        t0 += __shfl_down(t0, off);
        t1 += __shfl_down(t1, off);
    }
    __shared__ float red[2][2];
    int wave = j >> 6, lane = j & 63;
    if (lane == 0) { red[0][wave] = t0; red[1][wave] = t1; }
    __syncthreads();
    if (j == 0) out[b * 2 + 0] = red[0][0] + red[0][1] + bp[0];
    if (j == 1) out[b * 2 + 1] = red[1][0] + red[1][1] + bp[1];
}

// ---------------------------------------------------------------------------
extern "C" void kernel_launch(void* const* d_in, const int* in_sizes, int n_in,
                              void* d_out, int out_size, void* d_ws, size_t ws_size,
                              hipStream_t stream) {
    const int*   sent = (const int*)d_in[0];
    const float* adj  = (const float*)d_in[1];
    const float* emb  = (const float*)d_in[2];
    const float* W1   = (const float*)d_in[3];
    const float* b1   = (const float*)d_in[4];
    const float* W2   = (const float*)d_in[5];
    const float* b2   = (const float*)d_in[6];
    const float* W3   = (const float*)d_in[7];
    const float* b3   = (const float*)d_in[8];
    const float* Wp   = (const float*)d_in[9];
    const float* bp   = (const float*)d_in[10];
    float* out = (float*)d_out;

    char* ws = (char*)d_ws;
    float*    h1     = (float*)ws;                              // 16 MiB
    float*    h2     = (float*)(ws + ((size_t)16 << 20));       // 16 MiB
    char*     base   = ws + ((size_t)32 << 20);
    float*    invdeg = (float*)base;                            // M f32
    int*      nnz    = (int*)(base + (size_t)M_ * 4);
    ushort_t* idxl   = (ushort_t*)(base + (size_t)M_ * 8);      // 8 MiB
    float*    pooled = (float*)(base + (size_t)M_ * 8 + (size_t)M_ * CAP_ * 2);  // 64*128 f32

    k_adjidx<<<M_ / 4, 256, 0, stream>>>(adj, idxl, nnz, invdeg);

    k_layer<E_, true,  false><<<256, 256, 0, stream>>>(nullptr, sent, emb, W1, idxl, nnz, invdeg, b1, h1);
    k_layer<H_, false, false><<<256, 256, 0, stream>>>(h1, nullptr, nullptr, W2, idxl, nnz, invdeg, b2, h2);
    k_layer<H_, false, true ><<<256, 256, 0, stream>>>(h2, nullptr, nullptr, W3, idxl, nnz, invdeg, b3, pooled);

    k_final<<<B_, H_, 0, stream>>>(pooled, Wp, bp, out);
}

// Round 2
// 279.860 us; speedup vs baseline: 1.1679x; 1.1679x over previous
//
#include <hip/hip_runtime.h>

typedef unsigned short ushort_t;
typedef unsigned long long ull_t;

#define B_ 64
#define S_ 512
#define E_ 256
#define H_ 128
#define M_ (B_ * S_)   // 32768 rows
#define CAP_ 128       // max neighbor slots

// ---------------------------------------------------------------------------
// K1: neighbor lists from binary adj (float4 reads) + invdeg = 1/(nnz+1)
// ---------------------------------------------------------------------------
__global__ void k_adjidx(const float* __restrict__ adj,
                         ushort_t* __restrict__ idxl,
                         int* __restrict__ nnz,
                         float* __restrict__ invdeg) {
    int row  = blockIdx.x * 4 + (threadIdx.x >> 6);
    int lane = threadIdx.x & 63;
    const float4* arow = (const float4*)(adj + (size_t)row * S_);
    ushort_t* dst = idxl + (size_t)row * CAP_;
    int total = 0;
    #pragma unroll
    for (int c = 0; c < 2; ++c) {
        float4 v = arow[c * 64 + lane];
        float f[4] = {v.x, v.y, v.z, v.w};
        #pragma unroll
        for (int j = 0; j < 4; ++j) {
            unsigned long long m = __ballot(f[j] != 0.0f);
            if (f[j] != 0.0f) {
                int pos = total + __popcll(m & ((1ull << lane) - 1ull));
                if (pos < CAP_) dst[pos] = (ushort_t)(c * 256 + lane * 4 + j);
            }
            total += __popcll(m);
        }
    }
    if (lane == 0) {
        nnz[row] = total < CAP_ ? total : CAP_;
        invdeg[row] = 1.0f / (float)(total + 1);
    }
}

// ---------------------------------------------------------------------------
// K2: fused layer, 512 threads (8 waves -> 2 waves/SIMD at 1 block/CU).
//   Phase A: Ys[512][32] = X[b] @ W[cols]^T  (k-major LDS, 4x8 micro-tile)
//   Phase B: LDS neighbor gather + bias + invdeg + relu; nnz/invdeg/first
//            index-pack prefetched one row ahead, next pack prefetched
//            inside the neighbor loop (hides L2 latency under LDS gathers).
// 256 blocks (1/CU). LDS = 72K(Ys) + 32K(Xs dbuf) + 2K(Wsh) = 106.5K.
// ---------------------------------------------------------------------------
template <int K, bool GATHER, bool POOL>
__global__ __launch_bounds__(512, 2)
void k_layer(const float* __restrict__ X, const int* __restrict__ sent,
             const float* __restrict__ emb, const float* __restrict__ W,
             const ushort_t* __restrict__ idxl, const int* __restrict__ nnz,
             const float* __restrict__ invdeg, const float* __restrict__ bias,
             float* __restrict__ out) {
    __shared__ __align__(16) float Ys[S_ * 36];       // 73728 B, row stride 36
    __shared__ __align__(16) float Xs[2][8 * S_];     // 32768 B, k-major
    __shared__ __align__(16) float Wsh[2][8 * 32];    // 2048 B,  k-major

    const int tid = threadIdx.x;
    const int bid = blockIdx.x;
    const int xcd = bid & 7, slot = bid >> 3;
    const int b = xcd + 8 * (slot >> 2);
    const int cg = slot & 3;
    const int colBase = cg * 32;
    const int rowBase = b * S_;

    // ---- Phase A: GEMM ----
    // staging: thread loads rows {r0, r0+256}, k-quarter kq (1 float4 each)
    const int r0 = tid >> 1;              // 0..255
    const int kq = (tid & 1) * 4;         // 0 or 4
    const float* xp0;
    const float* xp1;
    if (GATHER) {
        xp0 = emb + (size_t)sent[rowBase + r0]       * K + kq;
        xp1 = emb + (size_t)sent[rowBase + r0 + 256] * K + kq;
    } else {
        xp0 = X + (size_t)(rowBase + r0)       * K + kq;
        xp1 = X + (size_t)(rowBase + r0 + 256) * K + kq;
    }
    const int wcol = (tid >> 1) & 31;
    const float* wp = W + (size_t)(colBase + wcol) * K + kq;

    // compute mapping: rows rg4..rg4+3, cols c0..c0+7
    const int rg4 = tid & ~3;             // 0..508
    const int c0  = (tid & 3) * 8;

    float acc[4][8] = {};
    float4 g0, g1;
    float4 wv = {0.f, 0.f, 0.f, 0.f};

    constexpr int NC = K / 8;

    // prologue: stage chunk 0
    g0 = *(const float4*)xp0;
    g1 = *(const float4*)xp1;
    if (tid < 64) wv = *(const float4*)wp;
    Xs[0][(kq + 0) * 512 + r0] = g0.x;
    Xs[0][(kq + 1) * 512 + r0] = g0.y;
    Xs[0][(kq + 2) * 512 + r0] = g0.z;
    Xs[0][(kq + 3) * 512 + r0] = g0.w;
    Xs[0][(kq + 0) * 512 + r0 + 256] = g1.x;
    Xs[0][(kq + 1) * 512 + r0 + 256] = g1.y;
    Xs[0][(kq + 2) * 512 + r0 + 256] = g1.z;
    Xs[0][(kq + 3) * 512 + r0 + 256] = g1.w;
    if (tid < 64) {
        Wsh[0][(kq + 0) * 32 + wcol] = wv.x;
        Wsh[0][(kq + 1) * 32 + wcol] = wv.y;
        Wsh[0][(kq + 2) * 32 + wcol] = wv.z;
        Wsh[0][(kq + 3) * 32 + wcol] = wv.w;
    }
    __syncthreads();

    #pragma unroll 1
    for (int c = 0; c < NC; ++c) {
        const int cur = c & 1;
        if (c + 1 < NC) {   // prefetch next chunk (global -> regs)
            g0 = *(const float4*)(xp0 + (c + 1) * 8);
            g1 = *(const float4*)(xp1 + (c + 1) * 8);
            if (tid < 64) wv = *(const float4*)(wp + (c + 1) * 8);
        }
        #pragma unroll
        for (int k = 0; k < 8; ++k) {
            const float4 xa = *(const float4*)&Xs[cur][k * 512 + rg4];
            const float4 wa = *(const float4*)&Wsh[cur][k * 32 + c0];
            const float4 wb = *(const float4*)&Wsh[cur][k * 32 + c0 + 4];
            const float xv[4]  = {xa.x, xa.y, xa.z, xa.w};
            const float wv8[8] = {wa.x, wa.y, wa.z, wa.w, wb.x, wb.y, wb.z, wb.w};
            #pragma unroll
            for (int i = 0; i < 4; ++i)
                #pragma unroll
                for (int j = 0; j < 8; ++j)
                    acc[i][j] += xv[i] * wv8[j];
        }
        if (c + 1 < NC) {   // regs -> other LDS buffer
            const int nb = cur ^ 1;
            Xs[nb][(kq + 0) * 512 + r0] = g0.x;
            Xs[nb][(kq + 1) * 512 + r0] = g0.y;
            Xs[nb][(kq + 2) * 512 + r0] = g0.z;
            Xs[nb][(kq + 3) * 512 + r0] = g0.w;
            Xs[nb][(kq + 0) * 512 + r0 + 256] = g1.x;
            Xs[nb][(kq + 1) * 512 + r0 + 256] = g1.y;
            Xs[nb][(kq + 2) * 512 + r0 + 256] = g1.z;
            Xs[nb][(kq + 3) * 512 + r0 + 256] = g1.w;
            if (tid < 64) {
                Wsh[nb][(kq + 0) * 32 + wcol] = wv.x;
                Wsh[nb][(kq + 1) * 32 + wcol] = wv.y;
                Wsh[nb][(kq + 2) * 32 + wcol] = wv.z;
                Wsh[nb][(kq + 3) * 32 + wcol] = wv.w;
            }
        }
        __syncthreads();
    }

    // epilogue: acc -> Ys slab
    #pragma unroll
    for (int i = 0; i < 4; ++i) {
        const int r = rg4 + i;
        *(float4*)&Ys[r * 36 + c0]     = make_float4(acc[i][0], acc[i][1], acc[i][2], acc[i][3]);
        *(float4*)&Ys[r * 36 + c0 + 4] = make_float4(acc[i][4], acc[i][5], acc[i][6], acc[i][7]);
    }
    __syncthreads();

    // ---- Phase B: LDS neighbor aggregation (+bias, invdeg, relu) ----
    const int rsub = tid >> 3;     // 0..63 rows in flight
    const int cc   = tid & 7;      // float4 chunk of the 32-col slab
    const float4* Ys4 = (const float4*)Ys;
    const float4 bv = *(const float4*)(bias + colBase + cc * 4);
    float4 pmax = {0.f, 0.f, 0.f, 0.f};   // post-relu values are >= 0

    int grow = rowBase + rsub;
    int n_cur = nnz[grow];
    float inv_cur = invdeg[grow];
    const ushort_t* il = idxl + (size_t)grow * CAP_;
    ull_t pk = *(const ull_t*)il;

    #pragma unroll 1
    for (int p = 0; p < 8; ++p) {
        const int r = p * 64 + rsub;
        int n_nxt = 0; float inv_nxt = 0.f; ull_t pk_nxt = 0;
        const ushort_t* il_nxt = il + 64 * CAP_;
        if (p < 7) {                       // prefetch next row's control data
            n_nxt = nnz[grow + 64];
            inv_nxt = invdeg[grow + 64];
            pk_nxt = *(const ull_t*)il_nxt;
        }
        float4 a = Ys4[r * 9 + cc];
        float4 a2 = {0.f, 0.f, 0.f, 0.f};
        const int n = n_cur;
        int i = 0;
        for (; i + 4 <= n; i += 4) {
            const ull_t pk_p = *(const ull_t*)(il + i + 4);  // prefetch next pack
            const int t0 = (int)(pk & 0xffffu);
            const int t1 = (int)((pk >> 16) & 0xffffu);
            const int t2 = (int)((pk >> 32) & 0xffffu);
            const int t3 = (int)((pk >> 48) & 0xffffu);
            const float4 v0 = Ys4[t0 * 9 + cc];
            const float4 v1 = Ys4[t1 * 9 + cc];
            const float4 v2 = Ys4[t2 * 9 + cc];
            const float4 v3 = Ys4[t3 * 9 + cc];
            a.x += v0.x + v1.x;  a.y += v0.y + v1.y;
            a.z += v0.z + v1.z;  a.w += v0.w + v1.w;
            a2.x += v2.x + v3.x; a2.y += v2.y + v3.y;
            a2.z += v2.z + v3.z; a2.w += v2.w + v3.w;
            pk = pk_p;
        }
        for (; i < n; ++i) {
            const int t = il[i];
            const float4 v = Ys4[t * 9 + cc];
            a.x += v.x; a.y += v.y; a.z += v.z; a.w += v.w;
        }
        a.x += a2.x; a.y += a2.y; a.z += a2.z; a.w += a2.w;
        float4 o;
        o.x = fmaxf((a.x + 2.0f * bv.x) * inv_cur, 0.0f);
        o.y = fmaxf((a.y + 2.0f * bv.y) * inv_cur, 0.0f);
        o.z = fmaxf((a.z + 2.0f * bv.z) * inv_cur, 0.0f);
        o.w = fmaxf((a.w + 2.0f * bv.w) * inv_cur, 0.0f);
        if (!POOL) {
            *(float4*)(out + (size_t)(rowBase + r) * H_ + colBase + cc * 4) = o;
        } else {
            pmax.x = fmaxf(pmax.x, o.x); pmax.y = fmaxf(pmax.y, o.y);
            pmax.z = fmaxf(pmax.z, o.z); pmax.w = fmaxf(pmax.w, o.w);
        }
        grow += 64; il = il_nxt;
        n_cur = n_nxt; inv_cur = inv_nxt; pk = pk_nxt;
    }

    if (POOL) {
        // full in-block pool over the 64 row-groups (reuse Xs as scratch)
        float4* smax = (float4*)Xs;
        smax[rsub * 8 + cc] = pmax;
        __syncthreads();
        if (tid < 8) {
            float4 m = smax[tid];
            #pragma unroll 8
            for (int q = 1; q < 64; ++q) {
                const float4 v = smax[q * 8 + tid];
                m.x = fmaxf(m.x, v.x); m.y = fmaxf(m.y, v.y);
                m.z = fmaxf(m.z, v.z); m.w = fmaxf(m.w, v.w);
            }
            *(float4*)(out + (size_t)b * H_ + colBase + tid * 4) = m;
        }
    }
}

// ---------------------------------------------------------------------------
// K3: logits[b,c] = pooled[b,:] . Wp[c,:] + bp[c]   (pooled is [64][128])
// ---------------------------------------------------------------------------
__global__ void k_final(const float* __restrict__ pooled,
                        const float* __restrict__ Wp,
                        const float* __restrict__ bp,
                        float* __restrict__ out) {
    int b = blockIdx.x, j = threadIdx.x;  // 128 threads
    float m = pooled[(size_t)b * H_ + j];
    float t0 = m * Wp[j];
    float t1 = m * Wp[H_ + j];
    #pragma unroll
    for (int off = 32; off > 0; off >>= 1) {
        t0 += __shfl_down(t0, off);
        t1 += __shfl_down(t1, off);
    }
    __shared__ float red[2][2];
    int wave = j >> 6, lane = j & 63;
    if (lane == 0) { red[0][wave] = t0; red[1][wave] = t1; }
    __syncthreads();
    if (j == 0) out[b * 2 + 0] = red[0][0] + red[0][1] + bp[0];
    if (j == 1) out[b * 2 + 1] = red[1][0] + red[1][1] + bp[1];
}

// ---------------------------------------------------------------------------
extern "C" void kernel_launch(void* const* d_in, const int* in_sizes, int n_in,
                              void* d_out, int out_size, void* d_ws, size_t ws_size,
                              hipStream_t stream) {
    const int*   sent = (const int*)d_in[0];
    const float* adj  = (const float*)d_in[1];
    const float* emb  = (const float*)d_in[2];
    const float* W1   = (const float*)d_in[3];
    const float* b1   = (const float*)d_in[4];
    const float* W2   = (const float*)d_in[5];
    const float* b2   = (const float*)d_in[6];
    const float* W3   = (const float*)d_in[7];
    const float* b3   = (const float*)d_in[8];
    const float* Wp   = (const float*)d_in[9];
    const float* bp   = (const float*)d_in[10];
    float* out = (float*)d_out;

    char* ws = (char*)d_ws;
    float*    h1     = (float*)ws;                              // 16 MiB
    float*    h2     = (float*)(ws + ((size_t)16 << 20));       // 16 MiB
    char*     base   = ws + ((size_t)32 << 20);
    float*    invdeg = (float*)base;                            // M f32
    int*      nnz    = (int*)(base + (size_t)M_ * 4);
    ushort_t* idxl   = (ushort_t*)(base + (size_t)M_ * 8);      // 8 MiB
    float*    pooled = (float*)(base + (size_t)M_ * 8 + (size_t)M_ * CAP_ * 2);  // 64*128 f32

    k_adjidx<<<M_ / 4, 256, 0, stream>>>(adj, idxl, nnz, invdeg);

    k_layer<E_, true,  false><<<256, 512, 0, stream>>>(nullptr, sent, emb, W1, idxl, nnz, invdeg, b1, h1);
    k_layer<H_, false, false><<<256, 512, 0, stream>>>(h1, nullptr, nullptr, W2, idxl, nnz, invdeg, b2, h2);
    k_layer<H_, false, true ><<<256, 512, 0, stream>>>(h2, nullptr, nullptr, W3, idxl, nnz, invdeg, b3, pooled);

    k_final<<<B_, H_, 0, stream>>>(pooled, Wp, bp, out);
}

// Round 3
// 279.137 us; speedup vs baseline: 1.1709x; 1.0026x over previous
//
#include <hip/hip_runtime.h>

typedef unsigned short ushort_t;
typedef unsigned long long ull_t;

#define B_ 64
#define S_ 512
#define E_ 256
#define H_ 128
#define M_ (B_ * S_)   // 32768 rows
#define CAP_ 128       // max neighbor slots

// ---------------------------------------------------------------------------
// K1: neighbor lists from binary adj (float4 reads) + invdeg = 1/(nnz+1)
// HBM-bound (reads 64MB of adj): ~11us ~= roofline, unchanged.
// ---------------------------------------------------------------------------
__global__ void k_adjidx(const float* __restrict__ adj,
                         ushort_t* __restrict__ idxl,
                         int* __restrict__ nnz,
                         float* __restrict__ invdeg) {
    int row  = blockIdx.x * 4 + (threadIdx.x >> 6);
    int lane = threadIdx.x & 63;
    const float4* arow = (const float4*)(adj + (size_t)row * S_);
    ushort_t* dst = idxl + (size_t)row * CAP_;
    int total = 0;
    #pragma unroll
    for (int c = 0; c < 2; ++c) {
        float4 v = arow[c * 64 + lane];
        float f[4] = {v.x, v.y, v.z, v.w};
        #pragma unroll
        for (int j = 0; j < 4; ++j) {
            unsigned long long m = __ballot(f[j] != 0.0f);
            if (f[j] != 0.0f) {
                int pos = total + __popcll(m & ((1ull << lane) - 1ull));
                if (pos < CAP_) dst[pos] = (ushort_t)(c * 256 + lane * 4 + j);
            }
            total += __popcll(m);
        }
    }
    if (lane == 0) {
        nnz[row] = total < CAP_ ? total : CAP_;
        invdeg[row] = 1.0f / (float)(total + 1);
    }
}

// ---------------------------------------------------------------------------
// K2: fused layer, 16-col slab per block -> LDS 73.75KB -> 2 blocks/CU
//     (16 waves/CU, 4 waves/SIMD). 512 blocks = 64 batches x 8 col-groups.
//   Phase A: Ys[512][16(+4 pad)] = X[b] @ W[cols]^T, 4x4 micro-tile,
//            X staged read-once through k-major LDS double-buffer.
//   Phase B: LDS neighbor gather (8 reads in flight) + bias/invdeg/relu.
//   The 2 resident blocks sit in different phases -> VALU/LDS overlap.
// ---------------------------------------------------------------------------
template <int K, bool GATHER, bool POOL>
__global__ __launch_bounds__(512, 4)
void k_layer(const float* __restrict__ X, const int* __restrict__ sent,
             const float* __restrict__ emb, const float* __restrict__ W,
             const ushort_t* __restrict__ idxl, const int* __restrict__ nnz,
             const float* __restrict__ invdeg, const float* __restrict__ bias,
             float* __restrict__ out) {
    __shared__ __align__(16) float Ys[S_ * 20];      // 40960 B, row stride 20
    __shared__ __align__(16) float Xs[2][8 * S_];    // 32768 B, k-major
    __shared__ __align__(16) float Wsh[2][8 * 16];   // 1024 B,  k-major

    const int tid = threadIdx.x;
    const int bid = blockIdx.x;
    const int b  = (bid & 7) + 8 * (bid >> 6);   // batch (xcd = b&7)
    const int cg = (bid >> 3) & 7;               // col-group
    const int colBase = cg * 16;
    const int rowBase = b * S_;

    // ---- Phase A: GEMM ----
    // staging: thread owns row (rowBase+tid), loads 8 k's per chunk
    const float* xp;
    if (GATHER) xp = emb + (size_t)sent[rowBase + tid] * K;
    else        xp = X + (size_t)(rowBase + tid) * K;

    const int wcol = tid & 15;                   // used by tid<32
    const int kq4  = (tid >> 4) * 4;             // 0 or 4 for tid<32
    const float* wp = W + (size_t)(colBase + wcol) * K + kq4;

    // compute mapping: rows rg4..rg4+3, cols c0..c0+3
    const int rg4 = tid & ~3;                    // 0..508
    const int c0  = (tid & 3) * 4;

    float acc[4][4] = {};
    float4 g0, g1;
    float4 wv = {0.f, 0.f, 0.f, 0.f};

    constexpr int NC = K / 8;

    // prologue: stage chunk 0
    g0 = *(const float4*)(xp);
    g1 = *(const float4*)(xp + 4);
    if (tid < 32) wv = *(const float4*)(wp);
    Xs[0][0 * 512 + tid] = g0.x;
    Xs[0][1 * 512 + tid] = g0.y;
    Xs[0][2 * 512 + tid] = g0.z;
    Xs[0][3 * 512 + tid] = g0.w;
    Xs[0][4 * 512 + tid] = g1.x;
    Xs[0][5 * 512 + tid] = g1.y;
    Xs[0][6 * 512 + tid] = g1.z;
    Xs[0][7 * 512 + tid] = g1.w;
    if (tid < 32) {
        Wsh[0][(kq4 + 0) * 16 + wcol] = wv.x;
        Wsh[0][(kq4 + 1) * 16 + wcol] = wv.y;
        Wsh[0][(kq4 + 2) * 16 + wcol] = wv.z;
        Wsh[0][(kq4 + 3) * 16 + wcol] = wv.w;
    }
    __syncthreads();

    #pragma unroll 1
    for (int c = 0; c < NC; ++c) {
        const int cur = c & 1;
        if (c + 1 < NC) {   // prefetch next chunk (global -> regs)
            g0 = *(const float4*)(xp + (c + 1) * 8);
            g1 = *(const float4*)(xp + (c + 1) * 8 + 4);
            if (tid < 32) wv = *(const float4*)(wp + (c + 1) * 8);
        }
        #pragma unroll
        for (int k = 0; k < 8; ++k) {
            const float4 xa = *(const float4*)&Xs[cur][k * 512 + rg4];
            const float4 wa = *(const float4*)&Wsh[cur][k * 16 + c0];
            const float xv[4] = {xa.x, xa.y, xa.z, xa.w};
            const float wf[4] = {wa.x, wa.y, wa.z, wa.w};
            #pragma unroll
            for (int i = 0; i < 4; ++i)
                #pragma unroll
                for (int j = 0; j < 4; ++j)
                    acc[i][j] += xv[i] * wf[j];
        }
        if (c + 1 < NC) {   // regs -> other LDS buffer
            const int nb = cur ^ 1;
            Xs[nb][0 * 512 + tid] = g0.x;
            Xs[nb][1 * 512 + tid] = g0.y;
            Xs[nb][2 * 512 + tid] = g0.z;
            Xs[nb][3 * 512 + tid] = g0.w;
            Xs[nb][4 * 512 + tid] = g1.x;
            Xs[nb][5 * 512 + tid] = g1.y;
            Xs[nb][6 * 512 + tid] = g1.z;
            Xs[nb][7 * 512 + tid] = g1.w;
            if (tid < 32) {
                Wsh[nb][(kq4 + 0) * 16 + wcol] = wv.x;
                Wsh[nb][(kq4 + 1) * 16 + wcol] = wv.y;
                Wsh[nb][(kq4 + 2) * 16 + wcol] = wv.z;
                Wsh[nb][(kq4 + 3) * 16 + wcol] = wv.w;
            }
        }
        __syncthreads();
    }

    // epilogue: acc -> Ys slab
    #pragma unroll
    for (int i = 0; i < 4; ++i)
        *(float4*)&Ys[(rg4 + i) * 20 + c0] =
            make_float4(acc[i][0], acc[i][1], acc[i][2], acc[i][3]);
    __syncthreads();

    // ---- Phase B: LDS neighbor aggregation (+bias, invdeg, relu) ----
    const int rsub = tid >> 2;     // 0..127 rows in flight
    const int cc   = tid & 3;      // float4 chunk of the 16-col slab
    const float4* Ys4 = (const float4*)Ys;      // row stride 5 float4s
    const float4 bv = *(const float4*)(bias + colBase + cc * 4);
    float4 pmax = {0.f, 0.f, 0.f, 0.f};   // post-relu values are >= 0

    #pragma unroll 1
    for (int p = 0; p < 4; ++p) {
        const int r = p * 128 + rsub;
        const int grow = rowBase + r;
        const int n = nnz[grow];
        const float inv = invdeg[grow];
        const ushort_t* il = idxl + (size_t)grow * CAP_;
        float4 a = Ys4[r * 5 + cc];
        float4 a2 = {0.f, 0.f, 0.f, 0.f};
        int i = 0;
        #pragma unroll 1
        for (; i + 8 <= n; i += 8) {
            const ull_t pka = *(const ull_t*)(il + i);
            const ull_t pkb = *(const ull_t*)(il + i + 4);
            const int t0 = (int)(pka & 0xffffu);
            const int t1 = (int)((pka >> 16) & 0xffffu);
            const int t2 = (int)((pka >> 32) & 0xffffu);
            const int t3 = (int)(pka >> 48);
            const int t4 = (int)(pkb & 0xffffu);
            const int t5 = (int)((pkb >> 16) & 0xffffu);
            const int t6 = (int)((pkb >> 32) & 0xffffu);
            const int t7 = (int)(pkb >> 48);
            const float4 v0 = Ys4[t0 * 5 + cc];
            const float4 v1 = Ys4[t1 * 5 + cc];
            const float4 v2 = Ys4[t2 * 5 + cc];
            const float4 v3 = Ys4[t3 * 5 + cc];
            const float4 v4 = Ys4[t4 * 5 + cc];
            const float4 v5 = Ys4[t5 * 5 + cc];
            const float4 v6 = Ys4[t6 * 5 + cc];
            const float4 v7 = Ys4[t7 * 5 + cc];
            // same pairing/order as the 4-pack loop (bitwise-stable)
            a.x += v0.x + v1.x;  a.y += v0.y + v1.y;
            a.z += v0.z + v1.z;  a.w += v0.w + v1.w;
            a2.x += v2.x + v3.x; a2.y += v2.y + v3.y;
            a2.z += v2.z + v3.z; a2.w += v2.w + v3.w;
            a.x += v4.x + v5.x;  a.y += v4.y + v5.y;
            a.z += v4.z + v5.z;  a.w += v4.w + v5.w;
            a2.x += v6.x + v7.x; a2.y += v6.y + v7.y;
            a2.z += v6.z + v7.z; a2.w += v6.w + v7.w;
        }
        for (; i + 4 <= n; i += 4) {
            const ull_t pka = *(const ull_t*)(il + i);
            const int t0 = (int)(pka & 0xffffu);
            const int t1 = (int)((pka >> 16) & 0xffffu);
            const int t2 = (int)((pka >> 32) & 0xffffu);
            const int t3 = (int)(pka >> 48);
            const float4 v0 = Ys4[t0 * 5 + cc];
            const float4 v1 = Ys4[t1 * 5 + cc];
            const float4 v2 = Ys4[t2 * 5 + cc];
            const float4 v3 = Ys4[t3 * 5 + cc];
            a.x += v0.x + v1.x;  a.y += v0.y + v1.y;
            a.z += v0.z + v1.z;  a.w += v0.w + v1.w;
            a2.x += v2.x + v3.x; a2.y += v2.y + v3.y;
            a2.z += v2.z + v3.z; a2.w += v2.w + v3.w;
        }
        for (; i < n; ++i) {
            const int t = il[i];
            const float4 v = Ys4[t * 5 + cc];
            a.x += v.x; a.y += v.y; a.z += v.z; a.w += v.w;
        }
        a.x += a2.x; a.y += a2.y; a.z += a2.z; a.w += a2.w;
        float4 o;
        o.x = fmaxf((a.x + 2.0f * bv.x) * inv, 0.0f);
        o.y = fmaxf((a.y + 2.0f * bv.y) * inv, 0.0f);
        o.z = fmaxf((a.z + 2.0f * bv.z) * inv, 0.0f);
        o.w = fmaxf((a.w + 2.0f * bv.w) * inv, 0.0f);
        if (!POOL) {
            *(float4*)(out + (size_t)grow * H_ + colBase + cc * 4) = o;
        } else {
            pmax.x = fmaxf(pmax.x, o.x); pmax.y = fmaxf(pmax.y, o.y);
            pmax.z = fmaxf(pmax.z, o.z); pmax.w = fmaxf(pmax.w, o.w);
        }
    }

    if (POOL) {
        // in-block pool over 128 row-groups (reuse Xs as scratch)
        float4* smax = (float4*)Xs;
        smax[tid] = pmax;                        // [rsub][cc] == tid
        __syncthreads();
        if (tid < 64) {
            const int gg = tid >> 2, c2 = tid & 3;
            float4 m = smax[gg * 4 + c2];
            #pragma unroll
            for (int j = 1; j < 8; ++j) {
                const float4 v = smax[(gg + 16 * j) * 4 + c2];
                m.x = fmaxf(m.x, v.x); m.y = fmaxf(m.y, v.y);
                m.z = fmaxf(m.z, v.z); m.w = fmaxf(m.w, v.w);
            }
            smax[512 + gg * 4 + c2] = m;
        }
        __syncthreads();
        if (tid < 4) {
            float4 m = smax[512 + tid];
            #pragma unroll
            for (int g = 1; g < 16; ++g) {
                const float4 v = smax[512 + g * 4 + tid];
                m.x = fmaxf(m.x, v.x); m.y = fmaxf(m.y, v.y);
                m.z = fmaxf(m.z, v.z); m.w = fmaxf(m.w, v.w);
            }
            *(float4*)(out + (size_t)b * H_ + colBase + tid * 4) = m;
        }
    }
}

// ---------------------------------------------------------------------------
// K3: logits[b,c] = pooled[b,:] . Wp[c,:] + bp[c]   (pooled is [64][128])
// ---------------------------------------------------------------------------
__global__ void k_final(const float* __restrict__ pooled,
                        const float* __restrict__ Wp,
                        const float* __restrict__ bp,
                        float* __restrict__ out) {
    int b = blockIdx.x, j = threadIdx.x;  // 128 threads
    float m = pooled[(size_t)b * H_ + j];
    float t0 = m * Wp[j];
    float t1 = m * Wp[H_ + j];
    #pragma unroll
    for (int off = 32; off > 0; off >>= 1) {
        t0 += __shfl_down(t0, off);
        t1 += __shfl_down(t1, off);
    }
    __shared__ float red[2][2];
    int wave = j >> 6, lane = j & 63;
    if (lane == 0) { red[0][wave] = t0; red[1][wave] = t1; }
    __syncthreads();
    if (j == 0) out[b * 2 + 0] = red[0][0] + red[0][1] + bp[0];
    if (j == 1) out[b * 2 + 1] = red[1][0] + red[1][1] + bp[1];
}

// ---------------------------------------------------------------------------
extern "C" void kernel_launch(void* const* d_in, const int* in_sizes, int n_in,
                              void* d_out, int out_size, void* d_ws, size_t ws_size,
                              hipStream_t stream) {
    const int*   sent = (const int*)d_in[0];
    const float* adj  = (const float*)d_in[1];
    const float* emb  = (const float*)d_in[2];
    const float* W1   = (const float*)d_in[3];
    const float* b1   = (const float*)d_in[4];
    const float* W2   = (const float*)d_in[5];
    const float* b2   = (const float*)d_in[6];
    const float* W3   = (const float*)d_in[7];
    const float* b3   = (const float*)d_in[8];
    const float* Wp   = (const float*)d_in[9];
    const float* bp   = (const float*)d_in[10];
    float* out = (float*)d_out;

    char* ws = (char*)d_ws;
    float*    h1     = (float*)ws;                              // 16 MiB
    float*    h2     = (float*)(ws + ((size_t)16 << 20));       // 16 MiB
    char*     base   = ws + ((size_t)32 << 20);
    float*    invdeg = (float*)base;                            // M f32
    int*      nnz    = (int*)(base + (size_t)M_ * 4);
    ushort_t* idxl   = (ushort_t*)(base + (size_t)M_ * 8);      // 8 MiB
    float*    pooled = (float*)(base + (size_t)M_ * 8 + (size_t)M_ * CAP_ * 2);  // 64*128 f32

    k_adjidx<<<M_ / 4, 256, 0, stream>>>(adj, idxl, nnz, invdeg);

    k_layer<E_, true,  false><<<512, 512, 0, stream>>>(nullptr, sent, emb, W1, idxl, nnz, invdeg, b1, h1);
    k_layer<H_, false, false><<<512, 512, 0, stream>>>(h1, nullptr, nullptr, W2, idxl, nnz, invdeg, b2, h2);
    k_layer<H_, false, true ><<<512, 512, 0, stream>>>(h2, nullptr, nullptr, W3, idxl, nnz, invdeg, b3, pooled);

    k_final<<<B_, H_, 0, stream>>>(pooled, Wp, bp, out);
}